// Round 1
// baseline (6056.809 us; speedup 1.0000x reference)
//
#include <hip/hip_runtime.h>
#include <math.h>

// Problem constants
constexpr int Dc = 128;   // channels
constexpr int Kc = 512;   // codebook entries
constexpr int Bc = 8;     // batch

// ---------------------------------------------------------------------------
// BN (eval mode, running stats 0/1): y = x * g * rsqrt(1+eps) + b, optional relu
__global__ void bn_kernel(const float* __restrict__ in, float* __restrict__ out,
                          const float* __restrict__ gamma, const float* __restrict__ beta,
                          int C, int HW, int total, int relu) {
  int i = blockIdx.x * blockDim.x + threadIdx.x;
  if (i >= total) return;
  int c = (i / HW) % C;
  float s = gamma[c] * rsqrtf(1.0f + 1e-5f);
  float v = fmaf(in[i], s, beta[c]);
  if (relu) v = fmaxf(v, 0.0f);
  out[i] = v;
}

__global__ void add_kernel(const float* __restrict__ a, const float* __restrict__ b,
                           float* __restrict__ out, int total) {
  int i = blockIdx.x * blockDim.x + threadIdx.x;
  if (i >= total) return;
  out[i] = a[i] + b[i];
}

// ---------------------------------------------------------------------------
// AdderNet L1 "conv": out[b,co,oh,ow] = -sum_{c,kh,kw} |patch - w[co, c*k*k+kh*k+kw]|
// Padded patch elements are ZERO and contribute |w| (reference extracts padded
// patches first). prerelu applies relu to the input activation reads.
__global__ void adder2d_kernel(const float* __restrict__ x, const float* __restrict__ w,
                               float* __restrict__ out,
                               int Cin, int Hin, int Win, int Cout, int Hout, int Wout,
                               int k, int stride, int pad, int prerelu) {
  int i = blockIdx.x * blockDim.x + threadIdx.x;
  int total = Bc * Cout * Hout * Wout;
  if (i >= total) return;
  int ow = i % Wout; int t = i / Wout;
  int oh = t % Hout; t /= Hout;
  int co = t % Cout; int b  = t / Cout;
  int kk = k * k;
  const float* wrow = w + co * Cin * kk;
  int chw = Hin * Win;
  float acc = 0.f;
  for (int kh = 0; kh < k; ++kh) {
    int yi = oh * stride - pad + kh;
    bool yok = (yi >= 0) && (yi < Hin);
    for (int kw = 0; kw < k; ++kw) {
      int xi = ow * stride - pad + kw;
      bool ok = yok && (xi >= 0) && (xi < Win);
      const float* wp = wrow + kh * k + kw;
      if (ok) {
        const float* xp = x + (b * Cin * Hin + yi) * Win + xi;
        for (int c = 0; c < Cin; ++c) {
          float v = xp[c * chw];
          if (prerelu) v = fmaxf(v, 0.f);
          acc += fabsf(v - wp[c * kk]);
        }
      } else {
        for (int c = 0; c < Cin; ++c) acc += fabsf(wp[c * kk]);
      }
    }
  }
  out[i] = -acc;
}

// ---------------------------------------------------------------------------
// conv3x3, pad=1, stride=1, OIHW weights; optional relu on input reads
__global__ void conv3x3_kernel(const float* __restrict__ x, const float* __restrict__ w,
                               const float* __restrict__ bias, float* __restrict__ out,
                               int Cin, int H, int W, int Cout, int prerelu) {
  int i = blockIdx.x * blockDim.x + threadIdx.x;
  int total = Bc * Cout * H * W;
  if (i >= total) return;
  int ow = i % W; int t = i / W;
  int oh = t % H; t /= H;
  int co = t % Cout; int b = t / Cout;
  int chw = H * W;
  float acc = bias[co];
  for (int kh = 0; kh < 3; ++kh) {
    int yi = oh - 1 + kh;
    if (yi < 0 || yi >= H) continue;
    for (int kw = 0; kw < 3; ++kw) {
      int xi = ow - 1 + kw;
      if (xi < 0 || xi >= W) continue;
      const float* xp = x + (b * Cin * H + yi) * W + xi;
      const float* wp = w + co * Cin * 9 + kh * 3 + kw;
      for (int c = 0; c < Cin; ++c) {
        float v = xp[c * chw];
        if (prerelu) v = fmaxf(v, 0.f);
        acc = fmaf(v, wp[c * 9], acc);
      }
    }
  }
  out[i] = acc;
}

__global__ void conv1x1_kernel(const float* __restrict__ x, const float* __restrict__ w,
                               const float* __restrict__ bias, float* __restrict__ out,
                               int Cin, int HW, int Cout, int prerelu) {
  int i = blockIdx.x * blockDim.x + threadIdx.x;
  int total = Bc * Cout * HW;
  if (i >= total) return;
  int pix = i % HW; int t = i / HW;
  int co = t % Cout; int b = t / Cout;
  float acc = bias[co];
  const float* xp = x + b * Cin * HW + pix;
  const float* wp = w + co * Cin;
  for (int c = 0; c < Cin; ++c) {
    float v = xp[c * HW];
    if (prerelu) v = fmaxf(v, 0.f);
    acc = fmaf(v, wp[c], acc);
  }
  out[i] = acc;
}

// ---------------------------------------------------------------------------
// 2x bilinear upsample, align_corners=False (half-pixel), edge-renormalized
// (== clamp for scale 2): even p -> 0.25*in[m-1]+0.75*in[m]; odd -> 0.75/0.25.
__device__ __forceinline__ void up_coef(int p, int H, int& i0, int& i1, float& w0, float& w1) {
  int m = p >> 1;
  if ((p & 1) == 0) { i0 = (m > 0) ? m - 1 : 0; i1 = m; w0 = 0.25f; w1 = 0.75f; }
  else              { i0 = m; i1 = (m + 1 < H) ? m + 1 : H - 1; w0 = 0.75f; w1 = 0.25f; }
}

__global__ void up2x_kernel(const float* __restrict__ in, float* __restrict__ out,
                            int C, int H, int W) {
  int H2 = 2 * H, W2 = 2 * W;
  int i = blockIdx.x * blockDim.x + threadIdx.x;
  int total = Bc * C * H2 * W2;
  if (i >= total) return;
  int ow = i % W2; int t = i / W2;
  int oh = t % H2; t /= H2;
  int c = t % C; int b = t / C;
  int y0, y1, x0, x1; float wy0, wy1, wx0, wx1;
  up_coef(oh, H, y0, y1, wy0, wy1);
  up_coef(ow, W, x0, x1, wx0, wx1);
  const float* p = in + (b * C + c) * H * W;
  float v = wy0 * (wx0 * p[y0 * W + x0] + wx1 * p[y0 * W + x1])
          + wy1 * (wx0 * p[y1 * W + x0] + wx1 * p[y1 * W + x1]);
  out[i] = v;
}

// ---------------------------------------------------------------------------
// Final conv3x3 over an implicitly 2x-upsampled input, + bias + tanh.
// x: [B,Cin,Hs,Ws]; logical input to the conv is [B,Cin,2Hs,2Ws] (zero pad=1).
__global__ void conv3x3_up_tanh_kernel(const float* __restrict__ x, const float* __restrict__ w,
                                       const float* __restrict__ bias, float* __restrict__ out,
                                       int Cin, int Hs, int Ws, int Cout) {
  int H2 = 2 * Hs, W2 = 2 * Ws;
  int i = blockIdx.x * blockDim.x + threadIdx.x;
  int total = Bc * Cout * H2 * W2;
  if (i >= total) return;
  int ow = i % W2; int t = i / W2;
  int oh = t % H2; t /= H2;
  int co = t % Cout; int b = t / Cout;
  int chw = Hs * Ws;
  const float* xb = x + b * Cin * chw;
  float acc = bias[co];
  for (int kh = 0; kh < 3; ++kh) {
    int p = oh - 1 + kh;
    if (p < 0 || p >= H2) continue;
    int y0, y1; float wy0, wy1;
    up_coef(p, Hs, y0, y1, wy0, wy1);
    for (int kw = 0; kw < 3; ++kw) {
      int q = ow - 1 + kw;
      if (q < 0 || q >= W2) continue;
      int x0, x1; float wx0, wx1;
      up_coef(q, Ws, x0, x1, wx0, wx1);
      int o00 = y0 * Ws + x0, o01 = y0 * Ws + x1;
      int o10 = y1 * Ws + x0, o11 = y1 * Ws + x1;
      const float* wp = w + co * Cin * 9 + kh * 3 + kw;
      for (int c = 0; c < Cin; ++c) {
        const float* pc = xb + c * chw;
        float v = wy0 * fmaf(wx0, pc[o00], wx1 * pc[o01])
                + wy1 * fmaf(wx0, pc[o10], wx1 * pc[o11]);
        acc = fmaf(v, wp[c * 9], acc);
      }
    }
  }
  out[i] = tanhf(acc);
}

// ---------------------------------------------------------------------------
// VQ nearest-embedding: one 256-thread block per spatial point.
// d2 = |f|^2 - 2 f.E_k + |E_k|^2  (same expression as reference), first-min tie-break.
__global__ void vq_kernel(const float* __restrict__ z_e, const float* __restrict__ E,
                          float* __restrict__ emb, float* __restrict__ argmin_out,
                          int H, int W) {
  __shared__ float f[Dc];
  __shared__ float d2s[256];
  __shared__ int   ks[256];
  int n = blockIdx.x;
  int w_ = n % W; int t = n / W;
  int h = t % H; int b = t / H;
  int tid = threadIdx.x;
  int HW = H * W;
  const float* zp = z_e + (b * Dc) * HW + h * W + w_;
  if (tid < Dc) f[tid] = zp[tid * HW];
  __syncthreads();
  float f2 = 0.f;
  for (int d = 0; d < Dc; ++d) f2 += f[d] * f[d];
  float best = 3.4e38f; int bestk = 0;
  for (int kk = tid; kk < Kc; kk += 256) {
    float dot = 0.f, e2 = 0.f;
    for (int d = 0; d < Dc; ++d) {
      float ed = E[d * Kc + kk];   // coalesced across lanes
      dot += f[d] * ed;
      e2  += ed * ed;
    }
    float d2 = f2 - 2.f * dot + e2;
    if (d2 < best || (d2 == best && kk < bestk)) { best = d2; bestk = kk; }
  }
  d2s[tid] = best; ks[tid] = bestk;
  __syncthreads();
  for (int s = 128; s > 0; s >>= 1) {
    if (tid < s) {
      float ob = d2s[tid + s]; int ok = ks[tid + s];
      if (ob < d2s[tid] || (ob == d2s[tid] && ok < ks[tid])) { d2s[tid] = ob; ks[tid] = ok; }
    }
    __syncthreads();
  }
  int kbest = ks[0];
  if (tid == 0) argmin_out[n] = (float)kbest;
  if (tid < Dc) emb[(b * Dc + tid) * HW + h * W + w_] = E[tid * Kc + kbest];
}

// ---------------------------------------------------------------------------
extern "C" void kernel_launch(void* const* d_in, const int* in_sizes, int n_in,
                              void* d_out, int out_size, void* d_ws, size_t ws_size,
                              hipStream_t stream) {
  const float* x      = (const float*)d_in[0];
  const float* we1    = (const float*)d_in[1];
  const float* we2    = (const float*)d_in[2];
  const float* ae1_w1 = (const float*)d_in[3];
  const float* ae1_w2 = (const float*)d_in[4];
  const float* ae2_w1 = (const float*)d_in[5];
  const float* ae2_w2 = (const float*)d_in[6];
  const float* bn_g   = (const float*)d_in[7];   // [8,128]
  const float* bn_b   = (const float*)d_in[8];
  const float* embw   = (const float*)d_in[9];   // [128,512]
  const float* rd1_w1 = (const float*)d_in[10];
  const float* rd1_b1 = (const float*)d_in[11];
  const float* rd1_w2 = (const float*)d_in[12];
  const float* rd1_b2 = (const float*)d_in[13];
  const float* rd2_w1 = (const float*)d_in[14];
  const float* rd2_b1 = (const float*)d_in[15];
  const float* rd2_w2 = (const float*)d_in[16];
  const float* rd2_b2 = (const float*)d_in[17];
  const float* cd1_w  = (const float*)d_in[18];
  const float* cd1_b  = (const float*)d_in[19];
  const float* cd2_w  = (const float*)d_in[20];
  const float* cd2_b  = (const float*)d_in[21];

  // Workspace layout (floats): two 64x64 buffers + three 32x32 buffers = 44 MB
  float* W64a = (float*)d_ws;            // [8,128,64,64]
  float* W64b = W64a + 4194304;          // [8,128,64,64]
  float* Wa   = W64b + 4194304;          // [8,128,32,32]
  float* Wb   = Wa + 1048576;
  float* Wc   = Wb + 1048576;

  // Output layout: y | z_e | emb | argmin (all as float)
  float* out_y   = (float*)d_out;        // 8*3*128*128   = 393216
  float* out_ze  = out_y  + 393216;      // 8*128*32*32   = 1048576
  float* out_emb = out_ze + 1048576;     // 8*128*32*32   = 1048576
  float* out_am  = out_emb + 1048576;    // 8*32*32       = 8192

  const int TB = 256;
  auto nb = [](int n) { return (n + 255) / 256; };
  const int N64 = Bc * Dc * 64 * 64;     // 4194304
  const int N32 = Bc * Dc * 32 * 32;     // 1048576

  // ---------------- encoder ----------------
  adder2d_kernel<<<nb(N64), TB, 0, stream>>>(x, we1, W64a, 3, 128, 128, Dc, 64, 64, 4, 2, 1, 0);
  bn_kernel<<<nb(N64), TB, 0, stream>>>(W64a, W64a, bn_g + 0 * Dc, bn_b + 0 * Dc, Dc, 4096, N64, 1);

  adder2d_kernel<<<nb(N32), TB, 0, stream>>>(W64a, we2, Wa, Dc, 64, 64, Dc, 32, 32, 4, 2, 1, 0);
  bn_kernel<<<nb(N32), TB, 0, stream>>>(Wa, Wa, bn_g + 1 * Dc, bn_b + 1 * Dc, Dc, 1024, N32, 1);

  // adder resblock 1
  adder2d_kernel<<<nb(N32), TB, 0, stream>>>(Wa, ae1_w1, Wb, Dc, 32, 32, Dc, 32, 32, 3, 1, 1, 1);
  bn_kernel<<<nb(N32), TB, 0, stream>>>(Wb, Wb, bn_g + 2 * Dc, bn_b + 2 * Dc, Dc, 1024, N32, 1);
  adder2d_kernel<<<nb(N32), TB, 0, stream>>>(Wb, ae1_w2, Wc, Dc, 32, 32, Dc, 32, 32, 1, 1, 0, 0);
  add_kernel<<<nb(N32), TB, 0, stream>>>(Wa, Wc, Wa, N32);

  bn_kernel<<<nb(N32), TB, 0, stream>>>(Wa, Wa, bn_g + 3 * Dc, bn_b + 3 * Dc, Dc, 1024, N32, 0);

  // adder resblock 2
  adder2d_kernel<<<nb(N32), TB, 0, stream>>>(Wa, ae2_w1, Wb, Dc, 32, 32, Dc, 32, 32, 3, 1, 1, 1);
  bn_kernel<<<nb(N32), TB, 0, stream>>>(Wb, Wb, bn_g + 4 * Dc, bn_b + 4 * Dc, Dc, 1024, N32, 1);
  adder2d_kernel<<<nb(N32), TB, 0, stream>>>(Wb, ae2_w2, Wc, Dc, 32, 32, Dc, 32, 32, 1, 1, 0, 0);
  add_kernel<<<nb(N32), TB, 0, stream>>>(Wa, Wc, Wa, N32);

  // z_e = bn (gamma = 1/40 row)
  bn_kernel<<<nb(N32), TB, 0, stream>>>(Wa, out_ze, bn_g + 5 * Dc, bn_b + 5 * Dc, Dc, 1024, N32, 0);

  // ---------------- VQ ----------------
  vq_kernel<<<Bc * 32 * 32, 256, 0, stream>>>(out_ze, embw, out_emb, out_am, 32, 32);

  // ---------------- decoder (z_q == emb numerically) ----------------
  conv3x3_kernel<<<nb(N32), TB, 0, stream>>>(out_emb, rd1_w1, rd1_b1, Wb, Dc, 32, 32, Dc, 1);
  conv1x1_kernel<<<nb(N32), TB, 0, stream>>>(Wb, rd1_w2, rd1_b2, Wc, Dc, 1024, Dc, 1);
  add_kernel<<<nb(N32), TB, 0, stream>>>(out_emb, Wc, Wa, N32);

  bn_kernel<<<nb(N32), TB, 0, stream>>>(Wa, Wa, bn_g + 6 * Dc, bn_b + 6 * Dc, Dc, 1024, N32, 0);

  conv3x3_kernel<<<nb(N32), TB, 0, stream>>>(Wa, rd2_w1, rd2_b1, Wb, Dc, 32, 32, Dc, 1);
  conv1x1_kernel<<<nb(N32), TB, 0, stream>>>(Wb, rd2_w2, rd2_b2, Wc, Dc, 1024, Dc, 1);
  add_kernel<<<nb(N32), TB, 0, stream>>>(Wa, Wc, Wa, N32);

  up2x_kernel<<<nb(N64), TB, 0, stream>>>(Wa, W64a, Dc, 32, 32);
  conv3x3_kernel<<<nb(N64), TB, 0, stream>>>(W64a, cd1_w, cd1_b, W64b, Dc, 64, 64, Dc, 0);
  bn_kernel<<<nb(N64), TB, 0, stream>>>(W64b, W64b, bn_g + 7 * Dc, bn_b + 7 * Dc, Dc, 4096, N64, 1);

  // fused: up2x -> conv3x3(128->3) -> +bias -> tanh
  conv3x3_up_tanh_kernel<<<nb(Bc * 3 * 128 * 128), TB, 0, stream>>>(W64b, cd2_w, cd2_b, out_y, Dc, 64, 64, 3);
}

// Round 2
// 1975.163 us; speedup vs baseline: 3.0665x; 3.0665x over previous
//
#include <hip/hip_runtime.h>
#include <math.h>

// Problem constants
constexpr int Dc = 128;   // channels
constexpr int Kc = 512;   // codebook entries
constexpr int Bc = 8;     // batch

// ---------------------------------------------------------------------------
// BN (eval mode, running stats 0/1): y = x * g * rsqrt(1+eps) + b, optional relu
__global__ void bn_kernel(const float* __restrict__ in, float* __restrict__ out,
                          const float* __restrict__ gamma, const float* __restrict__ beta,
                          int C, int HW, int total, int relu) {
  int i = blockIdx.x * blockDim.x + threadIdx.x;
  if (i >= total) return;
  int c = (i / HW) % C;
  float s = gamma[c] * rsqrtf(1.0f + 1e-5f);
  float v = fmaf(in[i], s, beta[c]);
  if (relu) v = fmaxf(v, 0.0f);
  out[i] = v;
}

__global__ void add_kernel(const float* __restrict__ a, const float* __restrict__ b,
                           float* __restrict__ out, int total) {
  int i = blockIdx.x * blockDim.x + threadIdx.x;
  if (i >= total) return;
  out[i] = a[i] + b[i];
}

// ---------------------------------------------------------------------------
// AdderNet L1 "conv" with COB output channels per thread.
// out[b,co,oh,ow] = -sum_{c,kh,kw} |patch - w[co, c*K*K + kh*K + kw]|
// Out-of-window patch elements are ZERO (reference pads first) -> v=0 path.
template<int K, int STRIDE, int PAD, int COB, int PRERELU>
__global__ void adder2d_cob(const float* __restrict__ x, const float* __restrict__ w,
                            float* __restrict__ out,
                            int Cin, int Hin, int Win, int Cout, int Hout, int Wout) {
  int i = blockIdx.x * blockDim.x + threadIdx.x;
  int npix = Bc * Hout * Wout;
  int total = npix * (Cout / COB);
  if (i >= total) return;
  int pix = i % npix;
  int cb = __builtin_amdgcn_readfirstlane(i / npix);  // uniform: npix % 256 == 0
  int ow = pix % Wout; int t = pix / Wout;
  int oh = t % Hout;   int b = t / Hout;
  int co0 = cb * COB;
  constexpr int KK = K * K;
  float acc[COB];
#pragma unroll
  for (int j = 0; j < COB; ++j) acc[j] = 0.f;
  int chw = Hin * Win;
  const float* xb = x + b * Cin * chw;
  const float* wb = w + co0 * Cin * KK;
  for (int c = 0; c < Cin; ++c) {
    const float* xc = xb + c * chw;
    const float* wc = wb + c * KK;
#pragma unroll
    for (int kh = 0; kh < K; ++kh) {
      int yi = oh * STRIDE - PAD + kh;
      bool yok = (yi >= 0) & (yi < Hin);
#pragma unroll
      for (int kw = 0; kw < K; ++kw) {
        int xi = ow * STRIDE - PAD + kw;
        bool ok = yok & (xi >= 0) & (xi < Win);
        float v = ok ? xc[yi * Win + xi] : 0.f;
        if (PRERELU) v = fmaxf(v, 0.f);
#pragma unroll
        for (int j = 0; j < COB; ++j)
          acc[j] += fabsf(v - wc[j * Cin * KK + kh * K + kw]);
      }
    }
  }
  int hw = Hout * Wout;
  float* ob = out + (b * Cout + co0) * hw + oh * Wout + ow;
#pragma unroll
  for (int j = 0; j < COB; ++j) ob[j * hw] = -acc[j];
}

// ---------------------------------------------------------------------------
// conv3x3, pad=1, stride=1, OIHW weights, COB output channels per thread.
template<int COB, int PRERELU>
__global__ void conv3x3_cob(const float* __restrict__ x, const float* __restrict__ w,
                            const float* __restrict__ bias, float* __restrict__ out,
                            int Cin, int H, int W, int Cout) {
  int i = blockIdx.x * blockDim.x + threadIdx.x;
  int npix = Bc * H * W;
  int total = npix * (Cout / COB);
  if (i >= total) return;
  int pix = i % npix;
  int cb = __builtin_amdgcn_readfirstlane(i / npix);
  int ow = pix % W; int t = pix / W;
  int oh = t % H;   int b = t / H;
  int co0 = cb * COB;
  int hw = H * W;
  float acc[COB];
#pragma unroll
  for (int j = 0; j < COB; ++j) acc[j] = bias[co0 + j];
  const float* xb = x + b * Cin * hw;
  const float* wb = w + co0 * Cin * 9;
  for (int c = 0; c < Cin; ++c) {
    const float* xc = xb + c * hw;
    const float* wc = wb + c * 9;
#pragma unroll
    for (int kh = 0; kh < 3; ++kh) {
      int yi = oh - 1 + kh;
      bool yok = (yi >= 0) & (yi < H);
#pragma unroll
      for (int kw = 0; kw < 3; ++kw) {
        int xi = ow - 1 + kw;
        bool ok = yok & (xi >= 0) & (xi < W);
        float v = ok ? xc[yi * W + xi] : 0.f;   // zero-pad -> fma adds 0
        if (PRERELU) v = fmaxf(v, 0.f);
#pragma unroll
        for (int j = 0; j < COB; ++j)
          acc[j] = fmaf(v, wc[j * Cin * 9 + kh * 3 + kw], acc[j]);
      }
    }
  }
  float* ob = out + (b * Cout + co0) * hw + oh * W + ow;
#pragma unroll
  for (int j = 0; j < COB; ++j) ob[j * hw] = acc[j];
}

template<int COB, int PRERELU>
__global__ void conv1x1_cob(const float* __restrict__ x, const float* __restrict__ w,
                            const float* __restrict__ bias, float* __restrict__ out,
                            int Cin, int HW, int Cout) {
  int i = blockIdx.x * blockDim.x + threadIdx.x;
  int npix = Bc * HW;
  int total = npix * (Cout / COB);
  if (i >= total) return;
  int pix = i % npix;
  int cb = __builtin_amdgcn_readfirstlane(i / npix);
  int p = pix % HW; int b = pix / HW;
  int co0 = cb * COB;
  float acc[COB];
#pragma unroll
  for (int j = 0; j < COB; ++j) acc[j] = bias[co0 + j];
  const float* xp = x + b * Cin * HW + p;
  const float* wb = w + co0 * Cin;
  for (int c = 0; c < Cin; ++c) {
    float v = xp[c * HW];
    if (PRERELU) v = fmaxf(v, 0.f);
#pragma unroll
    for (int j = 0; j < COB; ++j)
      acc[j] = fmaf(v, wb[j * Cin + c], acc[j]);
  }
  float* ob = out + (b * Cout + co0) * HW + p;
#pragma unroll
  for (int j = 0; j < COB; ++j) ob[j * HW] = acc[j];
}

// ---------------------------------------------------------------------------
// 2x bilinear upsample, align_corners=False (clamped, weights 0.25/0.75)
__device__ __forceinline__ void up_coef(int p, int H, int& i0, int& i1, float& w0, float& w1) {
  int m = p >> 1;
  if ((p & 1) == 0) { i0 = (m > 0) ? m - 1 : 0; i1 = m; w0 = 0.25f; w1 = 0.75f; }
  else              { i0 = m; i1 = (m + 1 < H) ? m + 1 : H - 1; w0 = 0.75f; w1 = 0.25f; }
}

__global__ void up2x_kernel(const float* __restrict__ in, float* __restrict__ out,
                            int C, int H, int W) {
  int H2 = 2 * H, W2 = 2 * W;
  int i = blockIdx.x * blockDim.x + threadIdx.x;
  int total = Bc * C * H2 * W2;
  if (i >= total) return;
  int ow = i % W2; int t = i / W2;
  int oh = t % H2; t /= H2;
  int c = t % C; int b = t / C;
  int y0, y1, x0, x1; float wy0, wy1, wx0, wx1;
  up_coef(oh, H, y0, y1, wy0, wy1);
  up_coef(ow, W, x0, x1, wx0, wx1);
  const float* p = in + (b * C + c) * H * W;
  float v = wy0 * (wx0 * p[y0 * W + x0] + wx1 * p[y0 * W + x1])
          + wy1 * (wx0 * p[y1 * W + x0] + wx1 * p[y1 * W + x1]);
  out[i] = v;
}

// ---------------------------------------------------------------------------
// Fused: up2x -> conv3x3(Cin->Cout, pad=1) -> +bias -> tanh.
// One thread = one (b, co, 2x2 output quad). Per channel: 3x3 source window,
// 4x4 upsampled values via shared bilinear blends, 4 accumulators.
__global__ void conv3x3_up_tanh_quad(const float* __restrict__ x, const float* __restrict__ w,
                                     const float* __restrict__ bias, float* __restrict__ out,
                                     int Cin, int Hs, int Ws, int Cout) {
  int H2 = 2 * Hs, W2 = 2 * Ws;
  int nq = Hs * Ws;
  int i = blockIdx.x * blockDim.x + threadIdx.x;
  int total = Bc * Cout * nq;
  if (i >= total) return;
  int q = i % nq; int t = i / nq;
  int co = t % Cout; int b = t / Cout;
  int n = q % Ws, m = q / Ws;
  int rows[3] = { (m > 0) ? m - 1 : 0, m, (m + 1 < Hs) ? m + 1 : Hs - 1 };
  int cols[3] = { (n > 0) ? n - 1 : 0, n, (n + 1 < Ws) ? n + 1 : Ws - 1 };
  // conv zero-padding: upsampled row p = 2m-1+di must lie in [0,H2)
  float rv[4] = { (2 * m - 1 >= 0) ? 1.f : 0.f, 1.f, 1.f, (2 * m + 2 < H2) ? 1.f : 0.f };
  float cv[4] = { (2 * n - 1 >= 0) ? 1.f : 0.f, 1.f, 1.f, (2 * n + 2 < W2) ? 1.f : 0.f };
  float bco = bias[co];
  float acc[4] = { bco, bco, bco, bco };
  const float* xb = x + b * Cin * nq;
  const float* wb = w + co * Cin * 9;
  for (int c = 0; c < Cin; ++c) {
    const float* xc = xb + c * nq;
    float s[3][3];
#pragma unroll
    for (int a = 0; a < 3; ++a)
#pragma unroll
      for (int e = 0; e < 3; ++e) s[a][e] = xc[rows[a] * Ws + cols[e]];
    float rb[4][3];
#pragma unroll
    for (int e = 0; e < 3; ++e) {
      rb[0][e] = fmaf(0.75f, s[0][e], 0.25f * s[1][e]);  // p=2m-1 (odd)
      rb[1][e] = fmaf(0.25f, s[0][e], 0.75f * s[1][e]);  // p=2m   (even)
      rb[2][e] = fmaf(0.75f, s[1][e], 0.25f * s[2][e]);  // p=2m+1 (odd)
      rb[3][e] = fmaf(0.25f, s[1][e], 0.75f * s[2][e]);  // p=2m+2 (even)
    }
    float u[4][4];
#pragma unroll
    for (int di = 0; di < 4; ++di) {
      float rm = rv[di];
      u[di][0] = fmaf(0.75f, rb[di][0], 0.25f * rb[di][1]) * rm * cv[0];
      u[di][1] = fmaf(0.25f, rb[di][0], 0.75f * rb[di][1]) * rm * cv[1];
      u[di][2] = fmaf(0.75f, rb[di][1], 0.25f * rb[di][2]) * rm * cv[2];
      u[di][3] = fmaf(0.25f, rb[di][1], 0.75f * rb[di][2]) * rm * cv[3];
    }
    const float* wc = wb + c * 9;
#pragma unroll
    for (int kh = 0; kh < 3; ++kh)
#pragma unroll
      for (int kw = 0; kw < 3; ++kw) {
        float ww = wc[kh * 3 + kw];
        acc[0] = fmaf(u[kh][kw],         ww, acc[0]);
        acc[1] = fmaf(u[kh][kw + 1],     ww, acc[1]);
        acc[2] = fmaf(u[kh + 1][kw],     ww, acc[2]);
        acc[3] = fmaf(u[kh + 1][kw + 1], ww, acc[3]);
      }
  }
  float* ob = out + (b * Cout + co) * H2 * W2 + (2 * m) * W2 + 2 * n;
  ob[0] = tanhf(acc[0]);      ob[1] = tanhf(acc[1]);
  ob[W2] = tanhf(acc[2]);     ob[W2 + 1] = tanhf(acc[3]);
}

// ---------------------------------------------------------------------------
// VQ nearest-embedding: one 256-thread block per spatial point.
__global__ void vq_kernel(const float* __restrict__ z_e, const float* __restrict__ E,
                          float* __restrict__ emb, float* __restrict__ argmin_out,
                          int H, int W) {
  __shared__ float f[Dc];
  __shared__ float d2s[256];
  __shared__ int   ks[256];
  int n = blockIdx.x;
  int w_ = n % W; int t = n / W;
  int h = t % H; int b = t / H;
  int tid = threadIdx.x;
  int HW = H * W;
  const float* zp = z_e + (b * Dc) * HW + h * W + w_;
  if (tid < Dc) f[tid] = zp[tid * HW];
  __syncthreads();
  float f2 = 0.f;
  for (int d = 0; d < Dc; ++d) f2 += f[d] * f[d];
  float best = 3.4e38f; int bestk = 0;
  for (int kk = tid; kk < Kc; kk += 256) {
    float dot = 0.f, e2 = 0.f;
    for (int d = 0; d < Dc; ++d) {
      float ed = E[d * Kc + kk];
      dot += f[d] * ed;
      e2  += ed * ed;
    }
    float d2 = f2 - 2.f * dot + e2;
    if (d2 < best || (d2 == best && kk < bestk)) { best = d2; bestk = kk; }
  }
  d2s[tid] = best; ks[tid] = bestk;
  __syncthreads();
  for (int s = 128; s > 0; s >>= 1) {
    if (tid < s) {
      float ob = d2s[tid + s]; int ok = ks[tid + s];
      if (ob < d2s[tid] || (ob == d2s[tid] && ok < ks[tid])) { d2s[tid] = ob; ks[tid] = ok; }
    }
    __syncthreads();
  }
  int kbest = ks[0];
  if (tid == 0) argmin_out[n] = (float)kbest;
  if (tid < Dc) emb[(b * Dc + tid) * HW + h * W + w_] = E[tid * Kc + kbest];
}

// ---------------------------------------------------------------------------
extern "C" void kernel_launch(void* const* d_in, const int* in_sizes, int n_in,
                              void* d_out, int out_size, void* d_ws, size_t ws_size,
                              hipStream_t stream) {
  const float* x      = (const float*)d_in[0];
  const float* we1    = (const float*)d_in[1];
  const float* we2    = (const float*)d_in[2];
  const float* ae1_w1 = (const float*)d_in[3];
  const float* ae1_w2 = (const float*)d_in[4];
  const float* ae2_w1 = (const float*)d_in[5];
  const float* ae2_w2 = (const float*)d_in[6];
  const float* bn_g   = (const float*)d_in[7];   // [8,128]
  const float* bn_b   = (const float*)d_in[8];
  const float* embw   = (const float*)d_in[9];   // [128,512]
  const float* rd1_w1 = (const float*)d_in[10];
  const float* rd1_b1 = (const float*)d_in[11];
  const float* rd1_w2 = (const float*)d_in[12];
  const float* rd1_b2 = (const float*)d_in[13];
  const float* rd2_w1 = (const float*)d_in[14];
  const float* rd2_b1 = (const float*)d_in[15];
  const float* rd2_w2 = (const float*)d_in[16];
  const float* rd2_b2 = (const float*)d_in[17];
  const float* cd1_w  = (const float*)d_in[18];
  const float* cd1_b  = (const float*)d_in[19];
  const float* cd2_w  = (const float*)d_in[20];
  const float* cd2_b  = (const float*)d_in[21];

  // Workspace layout (floats): two 64x64 buffers + three 32x32 buffers = 44 MB
  float* W64a = (float*)d_ws;            // [8,128,64,64]
  float* W64b = W64a + 4194304;          // [8,128,64,64]
  float* Wa   = W64b + 4194304;          // [8,128,32,32]
  float* Wb   = Wa + 1048576;
  float* Wc   = Wb + 1048576;

  // Output layout: y | z_e | emb | argmin (all as float)
  float* out_y   = (float*)d_out;        // 8*3*128*128   = 393216
  float* out_ze  = out_y  + 393216;      // 8*128*32*32   = 1048576
  float* out_emb = out_ze + 1048576;     // 8*128*32*32   = 1048576
  float* out_am  = out_emb + 1048576;    // 8*32*32       = 8192

  const int TB = 256;
  auto nb = [](int n) { return (n + 255) / 256; };
  const int N64 = Bc * Dc * 64 * 64;     // 4194304
  const int N32 = Bc * Dc * 32 * 32;     // 1048576
  const int COB = 8;
  const int T64 = Bc * 64 * 64 * (Dc / COB);  // 524288 threads for 64x64 layers
  const int T32 = Bc * 32 * 32 * (Dc / COB);  // 131072 threads for 32x32 layers

  // ---------------- encoder ----------------
  adder2d_cob<4, 2, 1, COB, 0><<<nb(T64), TB, 0, stream>>>(x, we1, W64a, 3, 128, 128, Dc, 64, 64);
  bn_kernel<<<nb(N64), TB, 0, stream>>>(W64a, W64a, bn_g + 0 * Dc, bn_b + 0 * Dc, Dc, 4096, N64, 1);

  adder2d_cob<4, 2, 1, COB, 0><<<nb(T32), TB, 0, stream>>>(W64a, we2, Wa, Dc, 64, 64, Dc, 32, 32);
  bn_kernel<<<nb(N32), TB, 0, stream>>>(Wa, Wa, bn_g + 1 * Dc, bn_b + 1 * Dc, Dc, 1024, N32, 1);

  // adder resblock 1
  adder2d_cob<3, 1, 1, COB, 1><<<nb(T32), TB, 0, stream>>>(Wa, ae1_w1, Wb, Dc, 32, 32, Dc, 32, 32);
  bn_kernel<<<nb(N32), TB, 0, stream>>>(Wb, Wb, bn_g + 2 * Dc, bn_b + 2 * Dc, Dc, 1024, N32, 1);
  adder2d_cob<1, 1, 0, COB, 0><<<nb(T32), TB, 0, stream>>>(Wb, ae1_w2, Wc, Dc, 32, 32, Dc, 32, 32);
  add_kernel<<<nb(N32), TB, 0, stream>>>(Wa, Wc, Wa, N32);

  bn_kernel<<<nb(N32), TB, 0, stream>>>(Wa, Wa, bn_g + 3 * Dc, bn_b + 3 * Dc, Dc, 1024, N32, 0);

  // adder resblock 2
  adder2d_cob<3, 1, 1, COB, 1><<<nb(T32), TB, 0, stream>>>(Wa, ae2_w1, Wb, Dc, 32, 32, Dc, 32, 32);
  bn_kernel<<<nb(N32), TB, 0, stream>>>(Wb, Wb, bn_g + 4 * Dc, bn_b + 4 * Dc, Dc, 1024, N32, 1);
  adder2d_cob<1, 1, 0, COB, 0><<<nb(T32), TB, 0, stream>>>(Wb, ae2_w2, Wc, Dc, 32, 32, Dc, 32, 32);
  add_kernel<<<nb(N32), TB, 0, stream>>>(Wa, Wc, Wa, N32);

  // z_e = bn (gamma = 1/40 row)
  bn_kernel<<<nb(N32), TB, 0, stream>>>(Wa, out_ze, bn_g + 5 * Dc, bn_b + 5 * Dc, Dc, 1024, N32, 0);

  // ---------------- VQ ----------------
  vq_kernel<<<Bc * 32 * 32, 256, 0, stream>>>(out_ze, embw, out_emb, out_am, 32, 32);

  // ---------------- decoder (z_q == emb numerically) ----------------
  conv3x3_cob<COB, 1><<<nb(T32), TB, 0, stream>>>(out_emb, rd1_w1, rd1_b1, Wb, Dc, 32, 32, Dc);
  conv1x1_cob<COB, 1><<<nb(T32), TB, 0, stream>>>(Wb, rd1_w2, rd1_b2, Wc, Dc, 1024, Dc);
  add_kernel<<<nb(N32), TB, 0, stream>>>(out_emb, Wc, Wa, N32);

  bn_kernel<<<nb(N32), TB, 0, stream>>>(Wa, Wa, bn_g + 6 * Dc, bn_b + 6 * Dc, Dc, 1024, N32, 0);

  conv3x3_cob<COB, 1><<<nb(T32), TB, 0, stream>>>(Wa, rd2_w1, rd2_b1, Wb, Dc, 32, 32, Dc);
  conv1x1_cob<COB, 1><<<nb(T32), TB, 0, stream>>>(Wb, rd2_w2, rd2_b2, Wc, Dc, 1024, Dc);
  add_kernel<<<nb(N32), TB, 0, stream>>>(Wa, Wc, Wa, N32);

  up2x_kernel<<<nb(N64), TB, 0, stream>>>(Wa, W64a, Dc, 32, 32);
  conv3x3_cob<COB, 0><<<nb(T64), TB, 0, stream>>>(W64a, cd1_w, cd1_b, W64b, Dc, 64, 64, Dc);
  bn_kernel<<<nb(N64), TB, 0, stream>>>(W64b, W64b, bn_g + 7 * Dc, bn_b + 7 * Dc, Dc, 4096, N64, 1);

  // fused: up2x -> conv3x3(128->3) -> +bias -> tanh
  conv3x3_up_tanh_quad<<<nb(Bc * 3 * 64 * 64), TB, 0, stream>>>(W64b, cd2_w, cd2_b, out_y, Dc, 64, 64, 3);
}